// Round 25
// baseline (120.796 us; speedup 1.0000x reference)
//
#include <hip/hip_runtime.h>

// EntailmentSelfAttention: N=16, L=256, S=2, H=16, D=64, E=1024
//
// Pipeline (3 kernels):
//   K0 k_wot  : Wb[f][e'] = bf16(Wo[f][perm(e')]) (frozen, r17).
//   K1 k_attn : FULLY FUSED proj+stats+PV MFMA; k_proj DELETED.
//               r24: proj pinned at ~48us reading 256B-segments @8KB
//               stride from L3 at ~2.1 TB/s regardless of occupancy
//               (28->45% no change) -> pattern-capped. Fix = delete the
//               50MB kqvB write + 67MB read-back: project in-kernel.
//               Per nhs block (512 thr, 8 waves):
//                 prologue: stage Wk/Wv (resident) + Wq (transient);
//                 each wave MFMA-projects its own 32-q strip into Qp
//                 (transient LDS), loads its aq frags (wave-private),
//                 then Qp region is REUSED for Ks/vsT/Es/Zl.
//                 phase1 (Z): per slab, wave w projects K-subtile
//                 (lt=wid>>2, et=wid&3) from raw rows (2 MFMA) -> Ks;
//                 S^T + exp + shfl-reduced atomicAdd Z (r21 logic).
//                 phase2: reproject K + project V (->vsT transposed);
//                 S^T + att->Es + PV (r21 logic).
//               LDS 64.6KB -> 2 blocks/CU. mb16 in static region
//               (old union spot was inside Qp extent - clobber hazard).
//   K2 k_wo   : bf16 MFMA GEMM (frozen, r17).
//
// ws layout: Xb(ushort) @0, Wb(ushort) @ +4194304 f32-elems.

typedef __attribute__((ext_vector_type(8))) short bf16x8;
typedef __attribute__((ext_vector_type(4))) float f32x4;

__device__ inline ushort f2bf(float x) {
    uint u = __float_as_uint(x);
    u += 0x7FFFu + ((u >> 16) & 1u);
    return (ushort)(u >> 16);
}

__global__ __launch_bounds__(256) void k_wot(
    const float* __restrict__ Wo, ushort* __restrict__ Wb)
{
    const int f = blockIdx.x;          // 0..1023
    const int e4 = threadIdx.x * 4;    // e' base (d%4==0, fixed hr/sp)
    const int hr = e4 >> 7, sp = (e4 >> 6) & 1, d = e4 & 63;
    const float* wrow = Wo + (long)f * 1024 + hr * 128 + 2 * d + sp;
    ushort o[4] = {f2bf(wrow[0]), f2bf(wrow[2]), f2bf(wrow[4]), f2bf(wrow[6])};
    *(uint2*)(Wb + (long)f * 1024 + e4) = *(uint2*)o;
}

// Fused proj+stats+PV. LDS map (ushort offsets in smem[32288]):
//   WKS 0      : Wk [64][72]                (resident)
//   WVS 4608   : Wv [64][72]                (resident)
//   MB  9216   : mb16 (16 ints = 32 ush)    (resident)
//   UNI 9248   : union region, 23040 ush:
//     prologue: Qp [256][72] @ +0 (18432);  Wq [64][72] @ +18432
//     main:     Ks [32][72] @ +0 (2304); vsT [64][44] @ +2304 (2816);
//               Es [128][44] @ +5120 (5632); Zl (256 f32) @ +10752 (512)
#define WKS 0
#define WVS 4608
#define MBO 9216
#define UNI 9248

__global__ __launch_bounds__(512) void k_attn(
    const float* __restrict__ Av, const float* __restrict__ Ak,
    const float* __restrict__ Aq, const float* __restrict__ Wv,
    const float* __restrict__ Wk, const float* __restrict__ Wq,
    const int* __restrict__ mask, ushort* __restrict__ Xb)
{
    __shared__ ushort smem[32288];   // 64,576 B
    ushort* Qp  = smem + UNI;                 // [q][72]
    ushort* Wqs = smem + UNI + 18432;         // [e][72]
    ushort* Ks  = smem + UNI;                 // [l][72]
    ushort* vsT = smem + UNI + 2304;          // [d][44]
    ushort* Es  = smem + UNI + 5120;          // [r][44]
    float*  Zl  = (float*)&smem[UNI + 10752]; // [256]
    int*    mb16 = (int*)&smem[MBO];

    const int nhs = blockIdx.x;
    const int n = nhs >> 5, h = (nhs >> 1) & 15, s = nhs & 1;
    const long abase = (long)n * 524288 + s * 1024 + h * 64;
    const long slice = (long)nhs * 16384;
    const int tid = threadIdx.x;
    const int wid = tid >> 6, lane = tid & 63;
    const int lr = lane & 15, lk = lane >> 4;

    // ---- prologue: stage Wk, Wv, Wq (f32->bf16) + mask bits
#pragma unroll
    for (int w = 0; w < 2; ++w) {
        int idx = w * 512 + tid;
        int r = idx >> 4, c4 = (idx & 15) * 4;
        float4 vk = *(const float4*)(Wk + r * 64 + c4);
        float4 vv = *(const float4*)(Wv + r * 64 + c4);
        float4 vq = *(const float4*)(Wq + r * 64 + c4);
        ushort tk[4] = {f2bf(vk.x), f2bf(vk.y), f2bf(vk.z), f2bf(vk.w)};
        ushort tv[4] = {f2bf(vv.x), f2bf(vv.y), f2bf(vv.z), f2bf(vv.w)};
        ushort tq[4] = {f2bf(vq.x), f2bf(vq.y), f2bf(vq.z), f2bf(vq.w)};
        *(uint2*)&smem[WKS + r * 72 + c4] = *(uint2*)tk;
        *(uint2*)&smem[WVS + r * 72 + c4] = *(uint2*)tv;
        *(uint2*)&Wqs[r * 72 + c4] = *(uint2*)tq;
    }
    const int mrow = n * 524288 + (h >> 3) * 262144 + (h & 7) * 32 + s * 16;
    if (tid < 16) mb16[tid] = mask[mrow + tid];
    __syncthreads();

    // ---- project Q: wave's own 32-q strip (2 q-tiles) -> Qp
#pragma unroll
    for (int qt = 0; qt < 2; ++qt) {
        const int qrow = wid * 32 + qt * 16 + lr;
        const float* arow = Aq + abase + (long)qrow * 2048;
        bf16x8 bfrag[2];
#pragma unroll
        for (int ks = 0; ks < 2; ++ks) {
            float4 v0 = *(const float4*)(arow + ks * 32 + lk * 8);
            float4 v1 = *(const float4*)(arow + ks * 32 + lk * 8 + 4);
            ushort t8[8] = {f2bf(v0.x), f2bf(v0.y), f2bf(v0.z), f2bf(v0.w),
                            f2bf(v1.x), f2bf(v1.y), f2bf(v1.z), f2bf(v1.w)};
            bfrag[ks] = *(bf16x8*)t8;
        }
#pragma unroll
        for (int et = 0; et < 4; ++et) {
            f32x4 acc;
#pragma unroll
            for (int rg = 0; rg < 4; ++rg) acc[rg] = 0.f;
#pragma unroll
            for (int ks = 0; ks < 2; ++ks) {
                bf16x8 wf = *(const bf16x8*)
                    &Wqs[(et * 16 + lr) * 72 + ks * 32 + lk * 8];
                acc = __builtin_amdgcn_mfma_f32_16x16x32_bf16(
                    wf, bfrag[ks], acc, 0, 0, 0);
            }
            ushort t4[4] = {f2bf(acc[0]), f2bf(acc[1]),
                            f2bf(acc[2]), f2bf(acc[3])};
            *(uint2*)&Qp[qrow * 72 + et * 16 + lk * 4] = *(uint2*)t4;
        }
    }
    __builtin_amdgcn_s_waitcnt(0);   // Qp rows are wave-private
    bf16x8 aq[2][2];
#pragma unroll
    for (int qt = 0; qt < 2; ++qt) {
        const int qb = wid * 32 + qt * 16;
        aq[qt][0] = *(const bf16x8*)&Qp[(qb + lr) * 72 + lk * 8];
        aq[qt][1] = *(const bf16x8*)&Qp[(qb + lr) * 72 + 32 + lk * 8];
    }
    __syncthreads();                 // all waves done with Qp
    if (tid < 256) Zl[tid] = 0.f;

    const float scale = 0.03125f;
    const int plt = wid >> 2, pet = wid & 3;   // this wave's proj subtile

    // ========== PHASE 1: Z accumulation ==========
#pragma unroll 1
    for (int sl = 0; sl < 8; ++sl) {
        __syncthreads();   // Zl ready (sl=0) / prev Ks reads done
        // project K subtile (lt=plt, et=pet): 2 MFMA -> Ks
        {
            const int lrow = sl * 32 + plt * 16 + lr;
            const float* arow = Ak + abase + (long)lrow * 2048;
            bf16x8 bfrag[2];
#pragma unroll
            for (int ks = 0; ks < 2; ++ks) {
                float4 v0 = *(const float4*)(arow + ks * 32 + lk * 8);
                float4 v1 = *(const float4*)(arow + ks * 32 + lk * 8 + 4);
                ushort t8[8] = {f2bf(v0.x), f2bf(v0.y), f2bf(v0.z), f2bf(v0.w),
                                f2bf(v1.x), f2bf(v1.y), f2bf(v1.z), f2bf(v1.w)};
                bfrag[ks] = *(bf16x8*)t8;
            }
            f32x4 acc;
#pragma unroll
            for (int rg = 0; rg < 4; ++rg) acc[rg] = 0.f;
#pragma unroll
            for (int ks = 0; ks < 2; ++ks) {
                bf16x8 wf = *(const bf16x8*)
                    &smem[WKS + (pet * 16 + lr) * 72 + ks * 32 + lk * 8];
                acc = __builtin_amdgcn_mfma_f32_16x16x32_bf16(
                    wf, bfrag[ks], acc, 0, 0, 0);
            }
            ushort t4[4] = {f2bf(acc[0]), f2bf(acc[1]),
                            f2bf(acc[2]), f2bf(acc[3])};
            *(uint2*)&Ks[(plt * 16 + lr) * 72 + pet * 16 + lk * 4] =
                *(uint2*)t4;
        }
        __syncthreads();

        float zlt[2] = {0.f, 0.f};
#pragma unroll
        for (int qt = 0; qt < 2; ++qt) {
            const int qb = wid * 32 + qt * 16;
            if (mb16[qb >> 4] == 0) continue;
#pragma unroll
            for (int lt = 0; lt < 2; ++lt) {
                f32x4 sacc;
#pragma unroll
                for (int rg = 0; rg < 4; ++rg) sacc[rg] = 0.f;
                bf16x8 b0 = *(const bf16x8*)
                    &Ks[(lt * 16 + lr) * 72 + lk * 8];
                bf16x8 b1 = *(const bf16x8*)
                    &Ks[(lt * 16 + lr) * 72 + 32 + lk * 8];
                sacc = __builtin_amdgcn_mfma_f32_16x16x32_bf16(
                    aq[qt][0], b0, sacc, 0, 0, 0);
                sacc = __builtin_amdgcn_mfma_f32_16x16x32_bf16(
                    aq[qt][1], b1, sacc, 0, 0, 0);
#pragma unroll
                for (int rg = 0; rg < 4; ++rg)
                    zlt[lt] += __expf(sacc[rg] * scale);
            }
        }
#pragma unroll
        for (int lt = 0; lt < 2; ++lt) {
            float v = zlt[lt];
            v += __shfl_xor(v, 16);
            v += __shfl_xor(v, 32);
            if (lk == 0)
                atomicAdd(&Zl[sl * 32 + lt * 16 + lr], v);
        }
    }

    __syncthreads();
    if (tid < 256) {
        float z = Zl[tid];
        Zl[tid] = (z > 0.f) ? 1.0f / z : 1.0f / 256.0f;
    }

    // ========== PHASE 2: att + PV ==========
    f32x4 acc0[4], acc1[4];
#pragma unroll
    for (int dt = 0; dt < 4; ++dt)
#pragma unroll
        for (int rg = 0; rg < 4; ++rg) { acc0[dt][rg] = 0.f; acc1[dt][rg] = 0.f; }

#pragma unroll 1
    for (int sl = 0; sl < 8; ++sl) {
        __syncthreads();   // Zl ready (sl=0) / prev Ks,vsT,Es reads done
        // project K subtile -> Ks AND V subtile -> vsT (transposed)
        {
            const int lrow = sl * 32 + plt * 16 + lr;
            const float* krow = Ak + abase + (long)lrow * 2048;
            const float* vrow = Av + abase + (long)lrow * 2048;
            bf16x8 kf[2], vf[2];
#pragma unroll
            for (int ks = 0; ks < 2; ++ks) {
                float4 k0 = *(const float4*)(krow + ks * 32 + lk * 8);
                float4 k1 = *(const float4*)(krow + ks * 32 + lk * 8 + 4);
                float4 w0 = *(const float4*)(vrow + ks * 32 + lk * 8);
                float4 w1 = *(const float4*)(vrow + ks * 32 + lk * 8 + 4);
                ushort tk[8] = {f2bf(k0.x), f2bf(k0.y), f2bf(k0.z), f2bf(k0.w),
                                f2bf(k1.x), f2bf(k1.y), f2bf(k1.z), f2bf(k1.w)};
                ushort tv[8] = {f2bf(w0.x), f2bf(w0.y), f2bf(w0.z), f2bf(w0.w),
                                f2bf(w1.x), f2bf(w1.y), f2bf(w1.z), f2bf(w1.w)};
                kf[ks] = *(bf16x8*)tk;
                vf[ks] = *(bf16x8*)tv;
            }
            f32x4 ka, va;
#pragma unroll
            for (int rg = 0; rg < 4; ++rg) { ka[rg] = 0.f; va[rg] = 0.f; }
#pragma unroll
            for (int ks = 0; ks < 2; ++ks) {
                bf16x8 wfk = *(const bf16x8*)
                    &smem[WKS + (pet * 16 + lr) * 72 + ks * 32 + lk * 8];
                bf16x8 wfv = *(const bf16x8*)
                    &smem[WVS + (pet * 16 + lr) * 72 + ks * 32 + lk * 8];
                ka = __builtin_amdgcn_mfma_f32_16x16x32_bf16(
                    wfk, kf[ks], ka, 0, 0, 0);
                va = __builtin_amdgcn_mfma_f32_16x16x32_bf16(
                    wfv, vf[ks], va, 0, 0, 0);
            }
            ushort t4[4] = {f2bf(ka[0]), f2bf(ka[1]),
                            f2bf(ka[2]), f2bf(ka[3])};
            *(uint2*)&Ks[(plt * 16 + lr) * 72 + pet * 16 + lk * 4] =
                *(uint2*)t4;
            // vsT[d][l]: d = pet*16+lk*4+rg, l = plt*16+lr
#pragma unroll
            for (int rg = 0; rg < 4; ++rg)
                vsT[(pet * 16 + lk * 4 + rg) * 44 + plt * 16 + lr] =
                    f2bf(va[rg]);
        }
        __syncthreads();

#pragma unroll
        for (int qt = 0; qt < 2; ++qt) {
            const int qb = wid * 32 + qt * 16;
            const bool live = (mb16[qb >> 4] != 0);
#pragma unroll
            for (int lt = 0; lt < 2; ++lt) {
                f32x4 sacc;
#pragma unroll
                for (int rg = 0; rg < 4; ++rg) sacc[rg] = 0.f;
                bf16x8 b0 = *(const bf16x8*)
                    &Ks[(lt * 16 + lr) * 72 + lk * 8];
                bf16x8 b1 = *(const bf16x8*)
                    &Ks[(lt * 16 + lr) * 72 + 32 + lk * 8];
                sacc = __builtin_amdgcn_mfma_f32_16x16x32_bf16(
                    aq[qt][0], b0, sacc, 0, 0, 0);
                sacc = __builtin_amdgcn_mfma_f32_16x16x32_bf16(
                    aq[qt][1], b1, sacc, 0, 0, 0);
                const int l = lt * 16 + lr;
                const float iz = Zl[sl * 32 + l];
#pragma unroll
                for (int rg = 0; rg < 4; ++rg) {
                    float ev = live ? __expf(sacc[rg] * scale) * iz : 0.f;
                    Es[(wid * 16 + lk * 4 + rg) * 44 + l] = f2bf(ev);
                }
            }
            __builtin_amdgcn_s_waitcnt(0);  // wave-local Es rows
            bf16x8 aP = *(const bf16x8*)&Es[(wid * 16 + lr) * 44 + lk * 8];
            f32x4* accp = (qt == 0) ? acc0 : acc1;
#pragma unroll
            for (int dt = 0; dt < 4; ++dt) {
                bf16x8 bV = *(const bf16x8*)
                    &vsT[(dt * 16 + lr) * 44 + lk * 8];
                accp[dt] = __builtin_amdgcn_mfma_f32_16x16x32_bf16(
                    aP, bV, accp[dt], 0, 0, 0);
            }
        }
    }

    // epilogue: D col=d, row=q-local -> Xb[nhs][q][d]
#pragma unroll
    for (int qt = 0; qt < 2; ++qt) {
        const f32x4* accp = (qt == 0) ? acc0 : acc1;
        const int qb = wid * 32 + qt * 16;
#pragma unroll
        for (int dt = 0; dt < 4; ++dt) {
#pragma unroll
            for (int rg = 0; rg < 4; ++rg) {
                const int q = qb + lk * 4 + rg;
                const int d = dt * 16 + lr;
                Xb[slice + (long)q * 64 + d] = f2bf(accp[dt][rg]);
            }
        }
    }
}

// MFMA k_wo (frozen, r17).
__global__ __launch_bounds__(512) void k_wo(
    const ushort* __restrict__ Xb, const ushort* __restrict__ Wb,
    const float* __restrict__ bo, float* __restrict__ out)
{
    __shared__ ushort Xs[128][72];
    __shared__ ushort Ws[128][72];
    const int b = blockIdx.x;
    const int by = b >> 3, bx = b & 7;
    const int r0 = by * 128, f0 = bx * 128;
    const int tid = threadIdx.x;
    const int wid = tid >> 6, lane = tid & 63;
    const int wr = wid >> 2, wc = wid & 3;
    const int lr = lane & 15, lk = lane >> 4;

    f32x4 acc[4][2];
#pragma unroll
    for (int rt = 0; rt < 4; ++rt)
#pragma unroll
        for (int ft = 0; ft < 2; ++ft)
#pragma unroll
            for (int rg = 0; rg < 4; ++rg) acc[rt][ft][rg] = 0.f;

    const int sr = tid >> 2, sc = (tid & 3) * 16;
    const int sR = r0 + sr;
    const int sn = sR >> 9, sq = (sR >> 1) & 255, ss2 = sR & 1;

#pragma unroll 1
    for (int eo = 0; eo < 1024; eo += 64) {
        const int hr = eo >> 7, sp = (eo >> 6) & 1;
        __syncthreads();
        {
            long xo = ((long)((sn * 16 + (ss2 * 8 + hr)) * 2 + sp)) * 16384 +
                      sq * 64 + sc;
            *(uint4*)&Xs[sr][sc] = *(const uint4*)(Xb + xo);
            *(uint4*)&Xs[sr][sc + 8] = *(const uint4*)(Xb + xo + 8);
            long wo = (long)(f0 + sr) * 1024 + eo + sc;
            *(uint4*)&Ws[sr][sc] = *(const uint4*)(Wb + wo);
            *(uint4*)&Ws[sr][sc + 8] = *(const uint4*)(Wb + wo + 8);
        }
        __syncthreads();

#pragma unroll
        for (int ks = 0; ks < 2; ++ks) {
            bf16x8 a[4], bb[2];
#pragma unroll
            for (int rt = 0; rt < 4; ++rt)
                a[rt] = *(const bf16x8*)
                    &Xs[wr * 64 + rt * 16 + lr][ks * 32 + lk * 8];
#pragma unroll
            for (int ft = 0; ft < 2; ++ft)
                bb[ft] = *(const bf16x8*)
                    &Ws[wc * 32 + ft * 16 + lr][ks * 32 + lk * 8];
#pragma unroll
            for (int rt = 0; rt < 4; ++rt)
#pragma unroll
                for (int ft = 0; ft < 2; ++ft)
                    acc[rt][ft] = __builtin_amdgcn_mfma_f32_16x16x32_bf16(
                        a[rt], bb[ft], acc[rt][ft], 0, 0, 0);
        }
    }

#pragma unroll
    for (int ft = 0; ft < 2; ++ft) {
        const int f = f0 + wc * 32 + ft * 16 + lr;
        const float bias = bo[f];
#pragma unroll
        for (int rt = 0; rt < 4; ++rt) {
#pragma unroll
            for (int rg = 0; rg < 4; ++rg) {
                const int r = r0 + wr * 64 + rt * 16 + lk * 4 + rg;
                out[(long)r * 1024 + f] = acc[rt][ft][rg] + bias;
            }
        }
    }
}

extern "C" void kernel_launch(void* const* d_in, const int* in_sizes, int n_in,
                              void* d_out, int out_size, void* d_ws,
                              size_t ws_size, hipStream_t stream)
{
    const float* vals = (const float*)d_in[0];
    const float* keys = (const float*)d_in[1];
    const float* qrys = (const float*)d_in[2];
    const int*   mask = (const int*)d_in[3];
    const float* Wv   = (const float*)d_in[4];
    const float* Wk   = (const float*)d_in[5];
    const float* Wq   = (const float*)d_in[6];
    const float* Wo   = (const float*)d_in[7];
    const float* bo   = (const float*)d_in[8];
    float* ws  = (float*)d_ws;
    ushort* Xb = (ushort*)(ws);
    ushort* Wb = (ushort*)(ws + 4194304);
    float* out = (float*)d_out;

    k_wot <<<1024, 256, 0, stream>>>(Wo, Wb);
    k_attn<<< 512, 512, 0, stream>>>(vals, keys, qrys, Wv, Wk, Wq, mask, Xb);
    k_wo  <<< 512, 512, 0, stream>>>(Xb, Wb, bo, out);
}

// Round 26
// 101.324 us; speedup vs baseline: 1.1922x; 1.1922x over previous
//
#include <hip/hip_runtime.h>

// EntailmentSelfAttention: N=16, L=256, S=2, H=16, D=64, E=1024
//
// Pipeline (4 kernels):
//   K0 k_wot  : Wb[f][e'] = bf16(Wo[f][perm(e')]) (frozen, r17).
//   K1 k_proj : v5 COALESCED-ROW staging MFMA. r22-r24: proj pinned at
//               ~49us reading 256B segs @8KB stride (block was per
//               (n,h,s)). But all 16 heads of a row are CONTIGUOUS (4KB).
//               Block = (n, s, 16-l chunk): stage 16 rows x 1024 f32 ->
//               bf16 As[16][1032] with fully-coalesced float4 loads; W x3
//               resident; wave w projects heads {2w,2w+1} (B-frags from
//               As, 2-way-free). Same MFMA/D-layout/store as r21-r24
//               (identical math -> identical absmax). 60.7KB LDS ->
//               2 blocks/CU, 16 waves/CU. r25 fusion regressed (120us:
//               strided loads serialized on barrier path) - reverted.
//   K2 k_attn : fused stats+PV MFMA v2 (frozen, r21/r23).
//   K3 k_wo   : bf16 MFMA GEMM (frozen, r17).
//
// ws layout (f32-elem offsets): kB @0, qB @4194304, vB @8388608,
//   Xb @12582912, Wb @16777216.

typedef __attribute__((ext_vector_type(8))) short bf16x8;
typedef __attribute__((ext_vector_type(4))) float f32x4;

__device__ inline ushort f2bf(float x) {
    uint u = __float_as_uint(x);
    u += 0x7FFFu + ((u >> 16) & 1u);
    return (ushort)(u >> 16);
}

__global__ __launch_bounds__(256) void k_wot(
    const float* __restrict__ Wo, ushort* __restrict__ Wb)
{
    const int f = blockIdx.x;          // 0..1023
    const int e4 = threadIdx.x * 4;    // e' base (d%4==0, fixed hr/sp)
    const int hr = e4 >> 7, sp = (e4 >> 6) & 1, d = e4 & 63;
    const float* wrow = Wo + (long)f * 1024 + hr * 128 + 2 * d + sp;
    ushort o[4] = {f2bf(wrow[0]), f2bf(wrow[2]), f2bf(wrow[4]), f2bf(wrow[6])};
    *(uint2*)(Wb + (long)f * 1024 + e4) = *(uint2*)o;
}

// Coalesced-row streaming MFMA projections v5.
// Block b = n*32 + s*16 + lc (n<16, s<2, lc<16); rows l0=lc*16 .. +15.
// 512 thr = 8 waves; wave w handles heads {2w, 2w+1}.
__global__ __launch_bounds__(512) void k_proj(
    const float* __restrict__ Av, const float* __restrict__ Ak,
    const float* __restrict__ Aq, const float* __restrict__ Wv,
    const float* __restrict__ Wk, const float* __restrict__ Wq,
    ushort* __restrict__ kB, ushort* __restrict__ qB,
    ushort* __restrict__ vB)
{
    __shared__ ushort As[16][1032];     // 33,024 B  [l-local][e=h*64+d]
    __shared__ ushort Wsb[3][64][72];   // 27,648 B  [m][e][d]
    const int b = blockIdx.x;
    const int n = b >> 5, s = (b >> 4) & 1, lc = b & 15;
    const int l0 = lc * 16;
    const float* Asrc[3] = {Av, Ak, Aq};
    const float* Wsrc[3] = {Wv, Wk, Wq};
    ushort* Bdst[3] = {vB, kB, qB};
    const int tid = threadIdx.x;
    const int wid = tid >> 6, lane = tid & 63;
    const int lr = lane & 15, lk = lane >> 4;

    // row base: A + n*524288 + (l0+r)*2048 + s*1024 + c  (c in [0,1024))
    const long rowbase = (long)n * 524288 + (long)l0 * 2048 + s * 1024;

    // stage all 3 W matrices (f32 -> bf16): 1024 f4 chunks each
#pragma unroll
    for (int m = 0; m < 3; ++m)
#pragma unroll
        for (int w = 0; w < 2; ++w) {
            int idx = w * 512 + tid;
            int r = idx >> 4, c4 = (idx & 15) * 4;
            float4 v = *(const float4*)(Wsrc[m] + r * 64 + c4);
            ushort t4[4] = {f2bf(v.x), f2bf(v.y), f2bf(v.z), f2bf(v.w)};
            *(uint2*)&Wsb[m][r][c4] = *(uint2*)t4;
        }

#pragma unroll 1
    for (int m = 0; m < 3; ++m) {
        __syncthreads();   // W staged (m=0) / prev compute done reading As
        // stage As: 16 rows x 1024 floats = 4096 f4, 8/thread, COALESCED
        const float* A = Asrc[m];
#pragma unroll
        for (int w = 0; w < 8; ++w) {
            int idx = w * 512 + tid;
            int r = idx >> 8, c4 = (idx & 255) * 4;
            float4 v = *(const float4*)(A + rowbase + (long)r * 2048 + c4);
            ushort t4[4] = {f2bf(v.x), f2bf(v.y), f2bf(v.z), f2bf(v.w)};
            *(uint2*)&As[r][c4] = *(uint2*)t4;
        }
        __syncthreads();

        // compute: wave's 2 heads x 4 e-tiles, K=64 (2 MFMA each)
        ushort* B = Bdst[m];
#pragma unroll
        for (int hh = 0; hh < 2; ++hh) {
            const int h = wid * 2 + hh;
            const long slice = ((long)((n * 16 + h) * 2 + s)) * 16384;
            bf16x8 bfrag[2];
#pragma unroll
            for (int ks = 0; ks < 2; ++ks)
                bfrag[ks] = *(const bf16x8*)
                    &As[lr][h * 64 + ks * 32 + lk * 8];
#pragma unroll
            for (int et = 0; et < 4; ++et) {
                f32x4 acc;
#pragma unroll
                for (int rg = 0; rg < 4; ++rg) acc[rg] = 0.f;
#pragma unroll
                for (int ks = 0; ks < 2; ++ks) {
                    bf16x8 wfrag = *(const bf16x8*)
                        &Wsb[m][et * 16 + lr][ks * 32 + lk * 8];
                    acc = __builtin_amdgcn_mfma_f32_16x16x32_bf16(
                        wfrag, bfrag[ks], acc, 0, 0, 0);
                }
                // D: col=l=l0+lr, row=e=et*16+lk*4+rg
                ushort t4[4] = {f2bf(acc[0]), f2bf(acc[1]),
                                f2bf(acc[2]), f2bf(acc[3])};
                *(uint2*)(B + slice + (long)(l0 + lr) * 64 +
                          et * 16 + lk * 4) = *(uint2*)t4;
            }
        }
    }
}

// Fused stats+PV v2 (frozen, r21/r23): one block per nhs, 512 thr = 8 waves.
__global__ __launch_bounds__(512) void k_attn(
    const ushort* __restrict__ kB, const ushort* __restrict__ qB,
    const ushort* __restrict__ vB, const int* __restrict__ mask,
    ushort* __restrict__ Xb)
{
    __shared__ ushort Ks[32][72];     //  4,608 B  [l][k]
    __shared__ ushort vsT[64][44];    //  5,632 B  [d][l]
    __shared__ ushort Es[128][44];    // 11,264 B  [wave-q][l]
    __shared__ float Zl[256];         //  1,024 B
    __shared__ int mb16[16];
    const int nhs = blockIdx.x;
    const int n = nhs >> 5, h = (nhs >> 1) & 15, s = nhs & 1;
    const long slice = (long)nhs * 16384;
    const int tid = threadIdx.x;
    const int wid = tid >> 6, lane = tid & 63;
    const int lr = lane & 15, lk = lane >> 4;

    bf16x8 aq[2][2];
#pragma unroll
    for (int qt = 0; qt < 2; ++qt) {
        const int qb = wid * 32 + qt * 16;
        aq[qt][0] = *(const bf16x8*)(qB + slice + (qb + lr) * 64 + lk * 8);
        aq[qt][1] = *(const bf16x8*)(qB + slice + (qb + lr) * 64 + 32 + lk * 8);
    }
    const int mrow = n * 524288 + (h >> 3) * 262144 + (h & 7) * 32 + s * 16;
    if (tid < 16) mb16[tid] = mask[mrow + tid];
    if (tid < 256) Zl[tid] = 0.f;

    const float scale = 0.03125f;

    // ========== PHASE 1: Z accumulation ==========
#pragma unroll 1
    for (int sl = 0; sl < 8; ++sl) {
        __syncthreads();
        if (tid < 256) {
            int r = tid >> 3, c8 = (tid & 7) * 8;
            *(uint4*)&Ks[r][c8] =
                *(const uint4*)(kB + slice + (sl * 32 + r) * 64 + c8);
        }
        __syncthreads();

        float zlt[2] = {0.f, 0.f};
#pragma unroll
        for (int qt = 0; qt < 2; ++qt) {
            const int qb = wid * 32 + qt * 16;
            if (mb16[qb >> 4] == 0) continue;
#pragma unroll
            for (int lt = 0; lt < 2; ++lt) {
                f32x4 sacc;
#pragma unroll
                for (int rg = 0; rg < 4; ++rg) sacc[rg] = 0.f;
                bf16x8 b0 = *(const bf16x8*)&Ks[lt * 16 + lr][lk * 8];
                bf16x8 b1 = *(const bf16x8*)&Ks[lt * 16 + lr][32 + lk * 8];
                sacc = __builtin_amdgcn_mfma_f32_16x16x32_bf16(
                    aq[qt][0], b0, sacc, 0, 0, 0);
                sacc = __builtin_amdgcn_mfma_f32_16x16x32_bf16(
                    aq[qt][1], b1, sacc, 0, 0, 0);
#pragma unroll
                for (int rg = 0; rg < 4; ++rg)
                    zlt[lt] += __expf(sacc[rg] * scale);
            }
        }
#pragma unroll
        for (int lt = 0; lt < 2; ++lt) {
            float v = zlt[lt];
            v += __shfl_xor(v, 16);
            v += __shfl_xor(v, 32);
            if (lk == 0)
                atomicAdd(&Zl[sl * 32 + lt * 16 + lr], v);
        }
    }

    __syncthreads();
    if (tid < 256) {
        float z = Zl[tid];
        Zl[tid] = (z > 0.f) ? 1.0f / z : 1.0f / 256.0f;
    }

    // ========== PHASE 2: att + PV ==========
    f32x4 acc0[4], acc1[4];
#pragma unroll
    for (int dt = 0; dt < 4; ++dt)
#pragma unroll
        for (int rg = 0; rg < 4; ++rg) { acc0[dt][rg] = 0.f; acc1[dt][rg] = 0.f; }

#pragma unroll 1
    for (int sl = 0; sl < 8; ++sl) {
        __syncthreads();
        if (tid < 256) {
            int r = tid >> 3, c8 = (tid & 7) * 8;
            *(uint4*)&Ks[r][c8] =
                *(const uint4*)(kB + slice + (sl * 32 + r) * 64 + c8);
        } else {
            int t = tid - 256;
            int l = t >> 3, d8 = (t & 7) * 8;
            uint4 vv = *(const uint4*)(vB + slice + (sl * 32 + l) * 64 + d8);
            ushort t8[8];
            *(uint4*)t8 = vv;
#pragma unroll
            for (int u = 0; u < 8; ++u) vsT[d8 + u][l] = t8[u];
        }
        __syncthreads();

#pragma unroll
        for (int qt = 0; qt < 2; ++qt) {
            const int qb = wid * 32 + qt * 16;
            const bool live = (mb16[qb >> 4] != 0);
#pragma unroll
            for (int lt = 0; lt < 2; ++lt) {
                f32x4 sacc;
#pragma unroll
                for (int rg = 0; rg < 4; ++rg) sacc[rg] = 0.f;
                bf16x8 b0 = *(const bf16x8*)&Ks[lt * 16 + lr][lk * 8];
                bf16x8 b1 = *(const bf16x8*)&Ks[lt * 16 + lr][32 + lk * 8];
                sacc = __builtin_amdgcn_mfma_f32_16x16x32_bf16(
                    aq[qt][0], b0, sacc, 0, 0, 0);
                sacc = __builtin_amdgcn_mfma_f32_16x16x32_bf16(
                    aq[qt][1], b1, sacc, 0, 0, 0);
                const int l = lt * 16 + lr;
                const float iz = Zl[sl * 32 + l];
#pragma unroll
                for (int rg = 0; rg < 4; ++rg) {
                    float ev = live ? __expf(sacc[rg] * scale) * iz : 0.f;
                    Es[wid * 16 + lk * 4 + rg][l] = f2bf(ev);
                }
            }
            __builtin_amdgcn_s_waitcnt(0);  // lgkmcnt(0): wave-local Es
            bf16x8 aP = *(const bf16x8*)&Es[wid * 16 + lr][lk * 8];
            f32x4* accp = (qt == 0) ? acc0 : acc1;
#pragma unroll
            for (int dt = 0; dt < 4; ++dt) {
                bf16x8 bV = *(const bf16x8*)&vsT[dt * 16 + lr][lk * 8];
                accp[dt] = __builtin_amdgcn_mfma_f32_16x16x32_bf16(
                    aP, bV, accp[dt], 0, 0, 0);
            }
        }
    }

#pragma unroll
    for (int qt = 0; qt < 2; ++qt) {
        const f32x4* accp = (qt == 0) ? acc0 : acc1;
        const int qb = wid * 32 + qt * 16;
#pragma unroll
        for (int dt = 0; dt < 4; ++dt) {
#pragma unroll
            for (int rg = 0; rg < 4; ++rg) {
                const int q = qb + lk * 4 + rg;
                const int d = dt * 16 + lr;
                Xb[slice + (long)q * 64 + d] = f2bf(accp[dt][rg]);
            }
        }
    }
}

// MFMA k_wo (frozen, r17).
__global__ __launch_bounds__(512) void k_wo(
    const ushort* __restrict__ Xb, const ushort* __restrict__ Wb,
    const float* __restrict__ bo, float* __restrict__ out)
{
    __shared__ ushort Xs[128][72];
    __shared__ ushort Ws[128][72];
    const int b = blockIdx.x;
    const int by = b >> 3, bx = b & 7;
    const int r0 = by * 128, f0 = bx * 128;
    const int tid = threadIdx.x;
    const int wid = tid >> 6, lane = tid & 63;
    const int wr = wid >> 2, wc = wid & 3;
    const int lr = lane & 15, lk = lane >> 4;

    f32x4 acc[4][2];
#pragma unroll
    for (int rt = 0; rt < 4; ++rt)
#pragma unroll
        for (int ft = 0; ft < 2; ++ft)
#pragma unroll
            for (int rg = 0; rg < 4; ++rg) acc[rt][ft][rg] = 0.f;

    const int sr = tid >> 2, sc = (tid & 3) * 16;
    const int sR = r0 + sr;
    const int sn = sR >> 9, sq = (sR >> 1) & 255, ss2 = sR & 1;

#pragma unroll 1
    for (int eo = 0; eo < 1024; eo += 64) {
        const int hr = eo >> 7, sp = (eo >> 6) & 1;
        __syncthreads();
        {
            long xo = ((long)((sn * 16 + (ss2 * 8 + hr)) * 2 + sp)) * 16384 +
                      sq * 64 + sc;
            *(uint4*)&Xs[sr][sc] = *(const uint4*)(Xb + xo);
            *(uint4*)&Xs[sr][sc + 8] = *(const uint4*)(Xb + xo + 8);
            long wo = (long)(f0 + sr) * 1024 + eo + sc;
            *(uint4*)&Ws[sr][sc] = *(const uint4*)(Wb + wo);
            *(uint4*)&Ws[sr][sc + 8] = *(const uint4*)(Wb + wo + 8);
        }
        __syncthreads();

#pragma unroll
        for (int ks = 0; ks < 2; ++ks) {
            bf16x8 a[4], bb[2];
#pragma unroll
            for (int rt = 0; rt < 4; ++rt)
                a[rt] = *(const bf16x8*)
                    &Xs[wr * 64 + rt * 16 + lr][ks * 32 + lk * 8];
#pragma unroll
            for (int ft = 0; ft < 2; ++ft)
                bb[ft] = *(const bf16x8*)
                    &Ws[wc * 32 + ft * 16 + lr][ks * 32 + lk * 8];
#pragma unroll
            for (int rt = 0; rt < 4; ++rt)
#pragma unroll
                for (int ft = 0; ft < 2; ++ft)
                    acc[rt][ft] = __builtin_amdgcn_mfma_f32_16x16x32_bf16(
                        a[rt], bb[ft], acc[rt][ft], 0, 0, 0);
        }
    }

#pragma unroll
    for (int ft = 0; ft < 2; ++ft) {
        const int f = f0 + wc * 32 + ft * 16 + lr;
        const float bias = bo[f];
#pragma unroll
        for (int rt = 0; rt < 4; ++rt) {
#pragma unroll
            for (int rg = 0; rg < 4; ++rg) {
                const int r = r0 + wr * 64 + rt * 16 + lk * 4 + rg;
                out[(long)r * 1024 + f] = acc[rt][ft][rg] + bias;
            }
        }
    }
}

extern "C" void kernel_launch(void* const* d_in, const int* in_sizes, int n_in,
                              void* d_out, int out_size, void* d_ws,
                              size_t ws_size, hipStream_t stream)
{
    const float* vals = (const float*)d_in[0];
    const float* keys = (const float*)d_in[1];
    const float* qrys = (const float*)d_in[2];
    const int*   mask = (const int*)d_in[3];
    const float* Wv   = (const float*)d_in[4];
    const float* Wk   = (const float*)d_in[5];
    const float* Wq   = (const float*)d_in[6];
    const float* Wo   = (const float*)d_in[7];
    const float* bo   = (const float*)d_in[8];
    float* ws  = (float*)d_ws;
    ushort* kB = (ushort*)(ws);
    ushort* qB = (ushort*)(ws + 4194304);
    ushort* vB = (ushort*)(ws + 8388608);
    ushort* Xb = (ushort*)(ws + 12582912);
    ushort* Wb = (ushort*)(ws + 16777216);
    float* out = (float*)d_out;

    k_wot <<<1024, 256, 0, stream>>>(Wo, Wb);
    k_proj<<< 512, 512, 0, stream>>>(vals, keys, qrys, Wv, Wk, Wq, kB, qB, vB);
    k_attn<<< 512, 512, 0, stream>>>(kB, qB, vB, mask, Xb);
    k_wo  <<< 512, 512, 0, stream>>>(Xb, Wb, bo, out);
}